// Round 11
// baseline (978.662 us; speedup 1.0000x reference)
//
#include <hip/hip_runtime.h>
#include <hip/hip_bf16.h>
#include <stdint.h>

#define DD 1024   // hidden dim
#define BB 4      // batch
#define TT 2048   // seq len
#define VV 16000  // vocab
#define LCH 8     // chunk length
#define NR 1024   // BB*(TT/LCH) rows, r = c*4 + b
#define PADR 512  // zero pad rows before E buffers
#define NPAD 16128
#define M1C ((size_t)DD * DD)

typedef __bf16 bf16_t;
typedef float f32x4_t __attribute__((ext_vector_type(4)));
typedef bf16_t bf16x8_t __attribute__((ext_vector_type(8)));
typedef bf16_t bf16x4_t __attribute__((ext_vector_type(4)));

#define KIND_SQ 0
#define KIND_ROUND 1
#define KIND_LEVEL 2
#define KIND_CARRY 3

__device__ __forceinline__ void gload16(const void* g, void* l) {
  __builtin_amdgcn_global_load_lds((const __attribute__((address_space(1))) void*)g,
                                   (__attribute__((address_space(3))) void*)l, 16, 0, 0);
}

// ---------------- fp32 -> bf16 convert (lm_w) ----------------
__global__ __launch_bounds__(256) void k_cvt(const float* __restrict__ src,
                                             bf16_t* __restrict__ dst, int n4) {
  int i = blockIdx.x * blockDim.x + threadIdx.x;
  int stride = gridDim.x * blockDim.x;
  for (; i < n4; i += stride) {
    float4 v = ((const float4*)src)[i];
    union { ushort4 u; bf16_t h[4]; } p;
    p.h[0] = (bf16_t)v.x; p.h[1] = (bf16_t)v.y;
    p.h[2] = (bf16_t)v.z; p.h[3] = (bf16_t)v.w;
    ((ushort4*)dst)[i] = p.u;
  }
}

// ---------------- chain: fp32-in/out split-bf16 MFMA GEMMs (round-5 verified) --
struct JobF {
  const float* A; const float* B; float* C; const float* Cin;
  int kind; int dlt;
};
struct JobsF { JobF j[8]; };

__global__ __launch_bounds__(256) void k_gatherF(const float* __restrict__ embed,
                                                 const int* __restrict__ ids,
                                                 float* __restrict__ slab0) {
  int r = blockIdx.x;
  int b = r & 3, c = r >> 2;
  int id = ids[b * TT + c * LCH];
  const float4* s = (const float4*)(embed + (size_t)id * DD);
  float4* d = (float4*)(slab0 + (size_t)r * DD);
  for (int i = threadIdx.x; i < DD / 4; i += blockDim.x) d[i] = s[i];
}

template <int NS>
__device__ __forceinline__ void swrite(char* base, int byteoff, float4 v) {
  float r0 = v.x, r1 = v.y, r2 = v.z, r3 = v.w;
#pragma unroll
  for (int p = 0; p < NS; ++p) {
    bf16x4_t h;
    h[0] = (bf16_t)r0; h[1] = (bf16_t)r1; h[2] = (bf16_t)r2; h[3] = (bf16_t)r3;
    *(bf16x4_t*)(base + p * 5120 + byteoff) = h;
    if (p + 1 < NS) {
      r0 -= (float)h[0]; r1 -= (float)h[1]; r2 -= (float)h[2]; r3 -= (float)h[3];
    }
  }
}

template <int NS, bool NN, int MODE>  // MODE: 0 plain,1 round,2 level,3 carry
__device__ __forceinline__ void mbodyF(bf16_t* __restrict__ SBb, const JobF& jb,
                                       const float* __restrict__ embed,
                                       const int* __restrict__ ids,
                                       bf16_t* __restrict__ hidden) {
  const float* A = jb.A;
  const float* Bm = jb.B;
  const int tid = threadIdx.x, lane = tid & 63, wave = tid >> 6;
  const int i0 = blockIdx.y * 64, j0 = blockIdx.x * 64;
  const int wm = (wave >> 1) * 32, wn = (wave & 1) * 32;
  char* Ap = (char*)SBb;
  char* Bp = Ap + NS * 5120;
  const int arow = tid >> 2;
  const int akb = (tid & 3) * 8;
  const int bj = tid & 63, bk4 = (tid >> 6) * 4;
  const int frow = lane & 15, fkb = (lane >> 4) * 16;
  f32x4_t acc[2][2] = {};

  const float* Aptr = A + (size_t)(i0 + arow) * DD + (tid & 3) * 4;
  const float* BptrNT = Bm + (size_t)(j0 + arow) * DD + (tid & 3) * 4;
  const float* BptrNN = Bm + (size_t)bk4 * DD + j0 + bj;

  float4 a0 = *(const float4*)(Aptr);
  float4 a1 = *(const float4*)(Aptr + 16);
  float4 b0, b1;
  float s0[4], s1[4];
  if (!NN) {
    b0 = *(const float4*)(BptrNT);
    b1 = *(const float4*)(BptrNT + 16);
  } else {
#pragma unroll
    for (int s = 0; s < 4; ++s) s0[s] = BptrNN[(size_t)s * DD];
#pragma unroll
    for (int s = 0; s < 4; ++s) s1[s] = BptrNN[(size_t)(16 + s) * DD];
  }

  for (int k0 = 0;;) {
    __syncthreads();
    swrite<NS>(Ap, arow * 80 + akb, a0);
    swrite<NS>(Ap, arow * 80 + akb + 32, a1);
    if (!NN) {
      swrite<NS>(Bp, arow * 80 + akb, b0);
      swrite<NS>(Bp, arow * 80 + akb + 32, b1);
    } else {
      float4 t0; t0.x = s0[0]; t0.y = s0[1]; t0.z = s0[2]; t0.w = s0[3];
      float4 t1; t1.x = s1[0]; t1.y = s1[1]; t1.z = s1[2]; t1.w = s1[3];
      swrite<NS>(Bp, bj * 80 + bk4 * 2, t0);
      swrite<NS>(Bp, bj * 80 + bk4 * 2 + 32, t1);
    }
    __syncthreads();
    int kn = k0 + 32;
    if (kn < DD) {
      a0 = *(const float4*)(Aptr + kn);
      a1 = *(const float4*)(Aptr + kn + 16);
      if (!NN) {
        b0 = *(const float4*)(BptrNT + kn);
        b1 = *(const float4*)(BptrNT + kn + 16);
      } else {
#pragma unroll
        for (int s = 0; s < 4; ++s) s0[s] = BptrNN[(size_t)(kn + s) * DD];
#pragma unroll
        for (int s = 0; s < 4; ++s) s1[s] = BptrNN[(size_t)(kn + 16 + s) * DD];
      }
    }
    bf16x8_t af[NS][2], bfx[NS][2];
#pragma unroll
    for (int p = 0; p < NS; ++p)
#pragma unroll
      for (int mf = 0; mf < 2; ++mf) {
        af[p][mf] = *(const bf16x8_t*)(Ap + p * 5120 + (wm + mf * 16 + frow) * 80 + fkb);
        bfx[p][mf] = *(const bf16x8_t*)(Bp + p * 5120 + (wn + mf * 16 + frow) * 80 + fkb);
      }
#pragma unroll
    for (int pa = 0; pa < NS; ++pa)
#pragma unroll
      for (int pb = 0; pb < NS; ++pb) {
        if (pa + pb < NS) {
#pragma unroll
          for (int mf = 0; mf < 2; ++mf)
#pragma unroll
            for (int nf = 0; nf < 2; ++nf)
              acc[mf][nf] = __builtin_amdgcn_mfma_f32_16x16x32_bf16(
                  af[pa][mf], bfx[pb][nf], acc[mf][nf], 0, 0, 0);
        }
      }
    k0 = kn;
    if (k0 >= DD) break;
  }

  const int ecol = lane & 15, er4 = (lane >> 4) * 4;
#pragma unroll
  for (int mf = 0; mf < 2; ++mf) {
#pragma unroll
    for (int nf = 0; nf < 2; ++nf) {
      const int rb = i0 + wm + mf * 16 + er4;
      const int cj = j0 + wn + nf * 16 + ecol;
#pragma unroll
      for (int rg = 0; rg < 4; ++rg) {
        const int ri = rb + rg;
        float v = acc[mf][nf][rg];
        if (MODE == 0) {
          jb.C[(size_t)ri * DD + cj] = v;
        } else if (MODE == 1) {
          int b = ri & 3, c = ri >> 2, t = c * LCH + jb.dlt;
          v += embed[(size_t)ids[b * TT + t] * DD + cj];
          jb.C[(size_t)ri * DD + cj] = v;
        } else if (MODE == 2) {
          v += jb.Cin[(size_t)ri * DD + cj];
          jb.C[(size_t)ri * DD + cj] = v;
        } else {
          int b = ri & 3, c = ri >> 2, t = c * LCH + jb.dlt;
          hidden[((size_t)b * TT + t) * DD + cj] =
              (bf16_t)(v + jb.Cin[(size_t)ri * DD + cj]);
        }
      }
    }
  }
}

__global__ __launch_bounds__(256, 2) void k_multiF(JobsF jobs,
                                                   const float* __restrict__ embed,
                                                   const int* __restrict__ ids,
                                                   bf16_t* __restrict__ hidden) {
  __shared__ __align__(16) bf16_t SBb[6 * 2560];
  const JobF& jb = jobs.j[blockIdx.z];
  if (jb.kind == KIND_SQ)
    mbodyF<3, true, 0>(SBb, jb, embed, ids, hidden);
  else if (jb.kind == KIND_ROUND)
    mbodyF<2, false, 1>(SBb, jb, embed, ids, hidden);
  else if (jb.kind == KIND_LEVEL)
    mbodyF<2, false, 2>(SBb, jb, embed, ids, hidden);
  else
    mbodyF<2, false, 3>(SBb, jb, embed, ids, hidden);
}

// ---------------- LM head: 128x256 tile, BK=32, 2-buf, 2 blocks/CU ----------
// Round-11: occupancy fix. 48 KiB LDS (2 bufs x 24 KB) -> 2 blocks/CU so a
// co-resident block covers each block's vmcnt/barrier stalls. Per tile:
// {read 8 frags; lgkmcnt(0)+barrier; stage(t+2) into freed buf; 16 MFMA;
// vmcnt(3)+barrier (tile t+1 landed)}. Swizzles unchanged (verified 0-conflict).
#define NTK 32

__global__ __launch_bounds__(512, 4) void k_lmhead4(
    const bf16_t* __restrict__ Ah, const bf16_t* __restrict__ Bw,
    const float* __restrict__ bias, float* __restrict__ Cout) {
  __shared__ __align__(16) char LB[2 * 24576];  // per buf: A 8KB + B 16KB
  const int tid = threadIdx.x, lane = tid & 63, wave = tid >> 6;
  const int wr = wave >> 2, wc = wave & 3;  // 2M x 4N
  // bijective XCD swizzle: nwg = 64*63 = 4032 = 8*504
  int orig = blockIdx.y * gridDim.x + blockIdx.x;
  int swz = (orig & 7) * 504 + (orig >> 3);
  int by = swz / 63, bx = swz % 63;
  const int m0 = by * 128, n0 = bx * 256;

  auto stage = [&](int t) {
    char* buf = LB + (size_t)(t & 1) * 24576;
    {  // A: 128 rows x 64B, 1 load/thread
      int tpos = tid * 16;
      int row = tpos >> 6;
      int scol = (tpos & 63) ^ (((row >> 1) & 3) << 4);
      gload16((const char*)Ah + ((size_t)(m0 + row) * DD + t * 32) * 2 + scol,
              buf + wave * 1024);
    }
#pragma unroll
    for (int p = 0; p < 2; ++p) {  // B: 256 rows x 64B, 2 loads/thread
      int tpos = p * 8192 + tid * 16;
      int row = tpos >> 6;
      int scol = (tpos & 63) ^ (((row >> 1) & 3) << 4);
      gload16((const char*)Bw + ((size_t)(n0 + row) * DD + t * 32) * 2 + scol,
              buf + 8192 + p * 8192 + wave * 1024);
    }
  };

  const int frow = lane & 15;
  const int c4b = (lane >> 4) * 16;
  f32x4_t acc[4][4] = {};

  // prologue: stage tiles 0,1 (6 loads/thread); vmcnt(3) => tile 0 landed
  stage(0); stage(1);
  asm volatile("s_waitcnt vmcnt(3)\ns_barrier" ::: "memory");

  for (int t = 0; t < NTK; ++t) {
    char* Abuf = LB + (size_t)(t & 1) * 24576;
    char* Bbuf = Abuf + 8192;
    bf16x8_t afr[4], bfr[4];
#pragma unroll
    for (int nf = 0; nf < 4; ++nf) {
      int r = wc * 64 + nf * 16 + frow;
      bfr[nf] = *(const bf16x8_t*)(Bbuf + r * 64 + (c4b ^ (((r >> 1) & 3) << 4)));
    }
#pragma unroll
    for (int mf = 0; mf < 4; ++mf) {
      int r = wr * 64 + mf * 16 + frow;
      afr[mf] = *(const bf16x8_t*)(Abuf + r * 64 + (c4b ^ (((r >> 1) & 3) << 4)));
    }
    // all reads of buf[t&1] complete before any wave's stage(t+2) DMA can land
    asm volatile("s_waitcnt lgkmcnt(0)\ns_barrier" ::: "memory");
    __builtin_amdgcn_sched_barrier(0);  // rule #18: fence reg-only MFMA hoist
    if (t + 2 < NTK) stage(t + 2);
    __builtin_amdgcn_s_setprio(1);
#pragma unroll
    for (int mf = 0; mf < 4; ++mf)
#pragma unroll
      for (int nf = 0; nf < 4; ++nf)
        acc[mf][nf] = __builtin_amdgcn_mfma_f32_16x16x32_bf16(
            afr[mf], bfr[nf], acc[mf][nf], 0, 0, 0);
    __builtin_amdgcn_s_setprio(0);
    // boundary: tile t+1 landed (3 newest = stage(t+2) stay in flight)
    if (t < NTK - 2) {
      asm volatile("s_waitcnt vmcnt(3)\ns_barrier" ::: "memory");
    } else if (t == NTK - 2) {
      asm volatile("s_waitcnt vmcnt(0)\ns_barrier" ::: "memory");
    }
  }

  const int ecol = lane & 15, er4 = (lane >> 4) * 4;
#pragma unroll
  for (int mf = 0; mf < 4; ++mf) {
#pragma unroll
    for (int nf = 0; nf < 4; ++nf) {
      int gm = m0 + wr * 64 + mf * 16 + er4;
      int gn = n0 + wc * 64 + nf * 16 + ecol;
      if (gn < VV) {
        float bv = bias[gn];
#pragma unroll
        for (int rg = 0; rg < 4; ++rg)
          Cout[(size_t)(gm + rg) * VV + gn] = acc[mf][nf][rg] + bv;
      }
    }
  }
}

// ---------------- host orchestration (round-5 verified schedule) -------------
extern "C" void kernel_launch(void* const* d_in, const int* in_sizes, int n_in,
                              void* d_out, int out_size, void* d_ws, size_t ws_size,
                              hipStream_t stream) {
  (void)in_sizes; (void)n_in; (void)out_size; (void)ws_size;
  const int* ids = (const int*)d_in[0];
  const float* embed = (const float*)d_in[1];
  const float* w_state = (const float*)d_in[2];
  const float* lm_w = (const float*)d_in[3];
  const float* lm_b = (const float*)d_in[4];
  float* out = (float*)d_out;

  const size_t M1 = M1C;
  float* PW = (float*)d_ws;                 // 8*M1 : PW + n*M1 = W^{n+1}
  float* Q = PW + 8 * M1;                   // 7*M1
  float* LOC = Q + 7 * M1;                  // 8*M1
  float* E0 = LOC + 8 * M1;
  float* E1 = E0 + (size_t)(PADR + NR) * DD;
  bf16_t* HID = (bf16_t*)(E1 + (size_t)(PADR + NR) * DD);
  bf16_t* LWB = HID + (size_t)BB * TT * DD;
  float* E0d = E0 + (size_t)PADR * DD;
  float* E1d = E1 + (size_t)PADR * DD;

  k_cvt<<<2048, 256, 0, stream>>>(lm_w, LWB, VV * DD / 4);
  hipMemsetAsync(LWB + (size_t)VV * DD, 0,
                 (size_t)(NPAD - VV) * DD * sizeof(bf16_t), stream);
  hipMemcpyAsync(PW, w_state, M1 * sizeof(float), hipMemcpyDeviceToDevice, stream);
  k_gatherF<<<NR, 256, 0, stream>>>(embed, ids, LOC);
  hipMemsetAsync(E0, 0, (size_t)PADR * DD * sizeof(float), stream);
  hipMemsetAsync(E1, 0, (size_t)PADR * DD * sizeof(float), stream);

  JobsF J{};
  J.j[0] = JobF{w_state, w_state, PW + M1, nullptr, KIND_SQ, 0};
  J.j[1] = JobF{LOC, w_state, LOC + M1, nullptr, KIND_ROUND, 1};
  k_multiF<<<dim3(16, 16, 2), 256, 0, stream>>>(J, embed, ids, HID);
  J.j[0] = JobF{PW + M1, w_state, PW + 2 * M1, nullptr, KIND_SQ, 0};
  J.j[1] = JobF{PW + M1, PW + M1, PW + 3 * M1, nullptr, KIND_SQ, 0};
  J.j[2] = JobF{LOC + M1, w_state, LOC + 2 * M1, nullptr, KIND_ROUND, 2};
  k_multiF<<<dim3(16, 16, 3), 256, 0, stream>>>(J, embed, ids, HID);
  J.j[0] = JobF{PW + 3 * M1, w_state, PW + 4 * M1, nullptr, KIND_SQ, 0};
  J.j[1] = JobF{PW + 3 * M1, PW + M1, PW + 5 * M1, nullptr, KIND_SQ, 0};
  J.j[2] = JobF{PW + 3 * M1, PW + 2 * M1, PW + 6 * M1, nullptr, KIND_SQ, 0};
  J.j[3] = JobF{PW + 3 * M1, PW + 3 * M1, PW + 7 * M1, nullptr, KIND_SQ, 0};
  J.j[4] = JobF{LOC + 2 * M1, w_state, LOC + 3 * M1, nullptr, KIND_ROUND, 3};
  k_multiF<<<dim3(16, 16, 5), 256, 0, stream>>>(J, embed, ids, HID);
  for (int d = 4; d <= 7; ++d) {
    const float* src = (d == 4) ? (PW + 7 * M1) : (Q + (size_t)(d - 5) * M1);
    J.j[0] = JobF{src, src, Q + (size_t)(d - 4) * M1, nullptr, KIND_SQ, 0};
    J.j[1] = JobF{LOC + (size_t)(d - 1) * M1, w_state, LOC + (size_t)d * M1,
                  nullptr, KIND_ROUND, d};
    k_multiF<<<dim3(16, 16, 2), 256, 0, stream>>>(J, embed, ids, HID);
  }
  hipMemcpyAsync(E0d, LOC + 7 * M1, M1 * sizeof(float),
                 hipMemcpyDeviceToDevice, stream);

  float* inp = E0d;
  float* outp = E1d;
  for (int k = 0; k < 8; ++k) {
    JobsF J2{};
    int nz = 0;
    if (k <= 2) {
      const float* src = Q + (size_t)(k + 3) * M1;
      J2.j[nz++] = JobF{src, src, Q + (size_t)(k + 4) * M1, nullptr, KIND_SQ, 0};
    }
    const float* Bq = (k == 0) ? (PW + 7 * M1) : (Q + (size_t)(k - 1) * M1);
    J2.j[nz++] = JobF{inp - (size_t)(4 << k) * DD, Bq, outp, inp, KIND_LEVEL, 0};
    k_multiF<<<dim3(16, 16, nz), 256, 0, stream>>>(J2, embed, ids, HID);
    float* t = inp; inp = outp; outp = t;
  }

  JobsF Jc{};
  for (int d = 0; d < 8; ++d)
    Jc.j[d] = JobF{inp - (size_t)4 * DD, PW + (size_t)d * M1, nullptr,
                   LOC + (size_t)d * M1, KIND_CARRY, d};
  k_multiF<<<dim3(16, 16, 8), 256, 0, stream>>>(Jc, embed, ids, HID);

  dim3 gl(NPAD / 256, (BB * TT) / 128);
  k_lmhead4<<<gl, 512, 0, stream>>>(HID, LWB, lm_b, out);
}

// Round 12
// 902.263 us; speedup vs baseline: 1.0847x; 1.0847x over previous
//
#include <hip/hip_runtime.h>
#include <hip/hip_bf16.h>
#include <stdint.h>

#define DD 1024   // hidden dim
#define BB 4      // batch
#define TT 2048   // seq len
#define VV 16000  // vocab
#define LCH 8     // chunk length
#define NR 1024   // BB*(TT/LCH) rows, r = c*4 + b
#define PADR 512  // zero pad rows before E buffers
#define NPAD 16128
#define M1C ((size_t)DD * DD)

typedef __bf16 bf16_t;
typedef float f32x4_t __attribute__((ext_vector_type(4)));
typedef bf16_t bf16x8_t __attribute__((ext_vector_type(8)));
typedef bf16_t bf16x4_t __attribute__((ext_vector_type(4)));

#define KIND_SQ 0
#define KIND_ROUND 1
#define KIND_LEVEL 2
#define KIND_CARRY 3

__device__ __forceinline__ void gload16(const void* g, void* l) {
  __builtin_amdgcn_global_load_lds((const __attribute__((address_space(1))) void*)g,
                                   (__attribute__((address_space(3))) void*)l, 16, 0, 0);
}

// ---------------- fp32 -> bf16 convert (lm_w) ----------------
__global__ __launch_bounds__(256) void k_cvt(const float* __restrict__ src,
                                             bf16_t* __restrict__ dst, int n4) {
  int i = blockIdx.x * blockDim.x + threadIdx.x;
  int stride = gridDim.x * blockDim.x;
  for (; i < n4; i += stride) {
    float4 v = ((const float4*)src)[i];
    union { ushort4 u; bf16_t h[4]; } p;
    p.h[0] = (bf16_t)v.x; p.h[1] = (bf16_t)v.y;
    p.h[2] = (bf16_t)v.z; p.h[3] = (bf16_t)v.w;
    ((ushort4*)dst)[i] = p.u;
  }
}

// ---------------- chain: fp32-in/out split-bf16 MFMA GEMMs (round-5 verified) --
struct JobF {
  const float* A; const float* B; float* C; const float* Cin;
  int kind; int dlt;
};
struct JobsF { JobF j[8]; };

__global__ __launch_bounds__(256) void k_gatherF(const float* __restrict__ embed,
                                                 const int* __restrict__ ids,
                                                 float* __restrict__ slab0) {
  int r = blockIdx.x;
  int b = r & 3, c = r >> 2;
  int id = ids[b * TT + c * LCH];
  const float4* s = (const float4*)(embed + (size_t)id * DD);
  float4* d = (float4*)(slab0 + (size_t)r * DD);
  for (int i = threadIdx.x; i < DD / 4; i += blockDim.x) d[i] = s[i];
}

template <int NS>
__device__ __forceinline__ void swrite(char* base, int byteoff, float4 v) {
  float r0 = v.x, r1 = v.y, r2 = v.z, r3 = v.w;
#pragma unroll
  for (int p = 0; p < NS; ++p) {
    bf16x4_t h;
    h[0] = (bf16_t)r0; h[1] = (bf16_t)r1; h[2] = (bf16_t)r2; h[3] = (bf16_t)r3;
    *(bf16x4_t*)(base + p * 5120 + byteoff) = h;
    if (p + 1 < NS) {
      r0 -= (float)h[0]; r1 -= (float)h[1]; r2 -= (float)h[2]; r3 -= (float)h[3];
    }
  }
}

template <int NS, bool NN, int MODE>  // MODE: 0 plain,1 round,2 level,3 carry
__device__ __forceinline__ void mbodyF(bf16_t* __restrict__ SBb, const JobF& jb,
                                       const float* __restrict__ embed,
                                       const int* __restrict__ ids,
                                       bf16_t* __restrict__ hidden) {
  const float* A = jb.A;
  const float* Bm = jb.B;
  const int tid = threadIdx.x, lane = tid & 63, wave = tid >> 6;
  const int i0 = blockIdx.y * 64, j0 = blockIdx.x * 64;
  const int wm = (wave >> 1) * 32, wn = (wave & 1) * 32;
  char* Ap = (char*)SBb;
  char* Bp = Ap + NS * 5120;
  const int arow = tid >> 2;
  const int akb = (tid & 3) * 8;
  const int bj = tid & 63, bk4 = (tid >> 6) * 4;
  const int frow = lane & 15, fkb = (lane >> 4) * 16;
  f32x4_t acc[2][2] = {};

  const float* Aptr = A + (size_t)(i0 + arow) * DD + (tid & 3) * 4;
  const float* BptrNT = Bm + (size_t)(j0 + arow) * DD + (tid & 3) * 4;
  const float* BptrNN = Bm + (size_t)bk4 * DD + j0 + bj;

  float4 a0 = *(const float4*)(Aptr);
  float4 a1 = *(const float4*)(Aptr + 16);
  float4 b0, b1;
  float s0[4], s1[4];
  if (!NN) {
    b0 = *(const float4*)(BptrNT);
    b1 = *(const float4*)(BptrNT + 16);
  } else {
#pragma unroll
    for (int s = 0; s < 4; ++s) s0[s] = BptrNN[(size_t)s * DD];
#pragma unroll
    for (int s = 0; s < 4; ++s) s1[s] = BptrNN[(size_t)(16 + s) * DD];
  }

  for (int k0 = 0;;) {
    __syncthreads();
    swrite<NS>(Ap, arow * 80 + akb, a0);
    swrite<NS>(Ap, arow * 80 + akb + 32, a1);
    if (!NN) {
      swrite<NS>(Bp, arow * 80 + akb, b0);
      swrite<NS>(Bp, arow * 80 + akb + 32, b1);
    } else {
      float4 t0; t0.x = s0[0]; t0.y = s0[1]; t0.z = s0[2]; t0.w = s0[3];
      float4 t1; t1.x = s1[0]; t1.y = s1[1]; t1.z = s1[2]; t1.w = s1[3];
      swrite<NS>(Bp, bj * 80 + bk4 * 2, t0);
      swrite<NS>(Bp, bj * 80 + bk4 * 2 + 32, t1);
    }
    __syncthreads();
    int kn = k0 + 32;
    if (kn < DD) {
      a0 = *(const float4*)(Aptr + kn);
      a1 = *(const float4*)(Aptr + kn + 16);
      if (!NN) {
        b0 = *(const float4*)(BptrNT + kn);
        b1 = *(const float4*)(BptrNT + kn + 16);
      } else {
#pragma unroll
        for (int s = 0; s < 4; ++s) s0[s] = BptrNN[(size_t)(kn + s) * DD];
#pragma unroll
        for (int s = 0; s < 4; ++s) s1[s] = BptrNN[(size_t)(kn + 16 + s) * DD];
      }
    }
    bf16x8_t af[NS][2], bfx[NS][2];
#pragma unroll
    for (int p = 0; p < NS; ++p)
#pragma unroll
      for (int mf = 0; mf < 2; ++mf) {
        af[p][mf] = *(const bf16x8_t*)(Ap + p * 5120 + (wm + mf * 16 + frow) * 80 + fkb);
        bfx[p][mf] = *(const bf16x8_t*)(Bp + p * 5120 + (wn + mf * 16 + frow) * 80 + fkb);
      }
#pragma unroll
    for (int pa = 0; pa < NS; ++pa)
#pragma unroll
      for (int pb = 0; pb < NS; ++pb) {
        if (pa + pb < NS) {
#pragma unroll
          for (int mf = 0; mf < 2; ++mf)
#pragma unroll
            for (int nf = 0; nf < 2; ++nf)
              acc[mf][nf] = __builtin_amdgcn_mfma_f32_16x16x32_bf16(
                  af[pa][mf], bfx[pb][nf], acc[mf][nf], 0, 0, 0);
        }
      }
    k0 = kn;
    if (k0 >= DD) break;
  }

  const int ecol = lane & 15, er4 = (lane >> 4) * 4;
#pragma unroll
  for (int mf = 0; mf < 2; ++mf) {
#pragma unroll
    for (int nf = 0; nf < 2; ++nf) {
      const int rb = i0 + wm + mf * 16 + er4;
      const int cj = j0 + wn + nf * 16 + ecol;
#pragma unroll
      for (int rg = 0; rg < 4; ++rg) {
        const int ri = rb + rg;
        float v = acc[mf][nf][rg];
        if (MODE == 0) {
          jb.C[(size_t)ri * DD + cj] = v;
        } else if (MODE == 1) {
          int b = ri & 3, c = ri >> 2, t = c * LCH + jb.dlt;
          v += embed[(size_t)ids[b * TT + t] * DD + cj];
          jb.C[(size_t)ri * DD + cj] = v;
        } else if (MODE == 2) {
          v += jb.Cin[(size_t)ri * DD + cj];
          jb.C[(size_t)ri * DD + cj] = v;
        } else {
          int b = ri & 3, c = ri >> 2, t = c * LCH + jb.dlt;
          hidden[((size_t)b * TT + t) * DD + cj] =
              (bf16_t)(v + jb.Cin[(size_t)ri * DD + cj]);
        }
      }
    }
  }
}

__global__ __launch_bounds__(256, 2) void k_multiF(JobsF jobs,
                                                   const float* __restrict__ embed,
                                                   const int* __restrict__ ids,
                                                   bf16_t* __restrict__ hidden) {
  __shared__ __align__(16) bf16_t SBb[6 * 2560];
  const JobF& jb = jobs.j[blockIdx.z];
  if (jb.kind == KIND_SQ)
    mbodyF<3, true, 0>(SBb, jb, embed, ids, hidden);
  else if (jb.kind == KIND_ROUND)
    mbodyF<2, false, 1>(SBb, jb, embed, ids, hidden);
  else if (jb.kind == KIND_LEVEL)
    mbodyF<2, false, 2>(SBb, jb, embed, ids, hidden);
  else
    mbodyF<2, false, 3>(SBb, jb, embed, ids, hidden);
}

// ---------------- LM head: round-5 verified kernel (330 us) ------------------
// 256x256 tile, BK=32, 4 LDS bufs, counted vmcnt(8), setprio around MFMA,
// both-sides XOR swizzle (0 bank conflicts measured), bijective XCD swizzle.
#define NTK 32

__global__ __launch_bounds__(512, 2) void k_lmhead2(
    const bf16_t* __restrict__ Ah, const bf16_t* __restrict__ Bw,
    const float* __restrict__ bias, float* __restrict__ Cout) {
  __shared__ __align__(16) char LB[4 * 32768];
  const int tid = threadIdx.x, lane = tid & 63, wave = tid >> 6;
  const int wr = wave >> 2, wc = wave & 3;
  int orig = blockIdx.y * gridDim.x + blockIdx.x;
  int swz = (orig & 7) * 252 + (orig >> 3);
  int by = swz / 63, bx = swz % 63;
  const int m0 = by * 256, n0 = bx * 256;

  const int srow = tid >> 2;
  const int scb = (tid & 3) * 16;

  auto stage = [&](int t) {
    char* buf = LB + (size_t)(t & 3) * 32768;
#pragma unroll
    for (int p = 0; p < 2; ++p) {
      int row = p * 128 + srow;
      int sw = ((row >> 1) & 3) << 4;
      gload16((const char*)Ah + ((size_t)(m0 + row) * DD + t * 32) * 2 + (scb ^ sw),
              buf + p * 8192 + wave * 1024);
      gload16((const char*)Bw + ((size_t)(n0 + row) * DD + t * 32) * 2 + (scb ^ sw),
              buf + 16384 + p * 8192 + wave * 1024);
    }
  };

  const int frow = lane & 15;
  const int c4b = (lane >> 4) * 16;
  f32x4_t acc[8][4] = {};

  stage(0); stage(1); stage(2);
  asm volatile("s_waitcnt vmcnt(8)\ns_barrier" ::: "memory");

  for (int t = 0; t < NTK; ++t) {
    char* Abuf = LB + (size_t)(t & 3) * 32768;
    char* Bbuf = Abuf + 16384;
    if (t + 3 < NTK) stage(t + 3);
    bf16x8_t afr[4], bfr[4];
#pragma unroll
    for (int nf = 0; nf < 4; ++nf) {
      int r = wc * 64 + nf * 16 + frow;
      bfr[nf] = *(const bf16x8_t*)(Bbuf + r * 64 + (c4b ^ (((r >> 1) & 3) << 4)));
    }
#pragma unroll
    for (int mf = 0; mf < 4; ++mf) {
      int r = wr * 128 + mf * 16 + frow;
      afr[mf] = *(const bf16x8_t*)(Abuf + r * 64 + (c4b ^ (((r >> 1) & 3) << 4)));
    }
    __builtin_amdgcn_s_setprio(1);
#pragma unroll
    for (int mf = 0; mf < 4; ++mf)
#pragma unroll
      for (int nf = 0; nf < 4; ++nf)
        acc[mf][nf] = __builtin_amdgcn_mfma_f32_16x16x32_bf16(
            afr[mf], bfr[nf], acc[mf][nf], 0, 0, 0);
    __builtin_amdgcn_s_setprio(0);
#pragma unroll
    for (int mf = 0; mf < 4; ++mf) {
      int r = wr * 128 + 64 + mf * 16 + frow;
      afr[mf] = *(const bf16x8_t*)(Abuf + r * 64 + (c4b ^ (((r >> 1) & 3) << 4)));
    }
    __builtin_amdgcn_s_setprio(1);
#pragma unroll
    for (int mf = 0; mf < 4; ++mf)
#pragma unroll
      for (int nf = 0; nf < 4; ++nf)
        acc[4 + mf][nf] = __builtin_amdgcn_mfma_f32_16x16x32_bf16(
            afr[mf], bfr[nf], acc[4 + mf][nf], 0, 0, 0);
    __builtin_amdgcn_s_setprio(0);
    if (t < NTK - 3) {
      asm volatile("s_waitcnt vmcnt(8)\ns_barrier" ::: "memory");
    } else if (t == NTK - 3) {
      asm volatile("s_waitcnt vmcnt(4)\ns_barrier" ::: "memory");
    } else if (t == NTK - 2) {
      asm volatile("s_waitcnt vmcnt(0)\ns_barrier" ::: "memory");
    }
  }

  const int ecol = lane & 15, er4 = (lane >> 4) * 4;
#pragma unroll
  for (int mf = 0; mf < 8; ++mf) {
#pragma unroll
    for (int nf = 0; nf < 4; ++nf) {
      int gm = m0 + wr * 128 + mf * 16 + er4;
      int gn = n0 + wc * 64 + nf * 16 + ecol;
      if (gn < VV) {
        float bv = bias[gn];
#pragma unroll
        for (int rg = 0; rg < 4; ++rg)
          Cout[(size_t)(gm + rg) * VV + gn] = acc[mf][nf][rg] + bv;
      }
    }
  }
}

// ---------------- host orchestration (round-5 verified schedule) -------------
extern "C" void kernel_launch(void* const* d_in, const int* in_sizes, int n_in,
                              void* d_out, int out_size, void* d_ws, size_t ws_size,
                              hipStream_t stream) {
  (void)in_sizes; (void)n_in; (void)out_size; (void)ws_size;
  const int* ids = (const int*)d_in[0];
  const float* embed = (const float*)d_in[1];
  const float* w_state = (const float*)d_in[2];
  const float* lm_w = (const float*)d_in[3];
  const float* lm_b = (const float*)d_in[4];
  float* out = (float*)d_out;

  const size_t M1 = M1C;
  float* PW = (float*)d_ws;                 // 8*M1 : PW + n*M1 = W^{n+1}
  float* Q = PW + 8 * M1;                   // 7*M1
  float* LOC = Q + 7 * M1;                  // 8*M1
  float* E0 = LOC + 8 * M1;
  float* E1 = E0 + (size_t)(PADR + NR) * DD;
  bf16_t* HID = (bf16_t*)(E1 + (size_t)(PADR + NR) * DD);
  bf16_t* LWB = HID + (size_t)BB * TT * DD;
  float* E0d = E0 + (size_t)PADR * DD;
  float* E1d = E1 + (size_t)PADR * DD;

  k_cvt<<<2048, 256, 0, stream>>>(lm_w, LWB, VV * DD / 4);
  hipMemsetAsync(LWB + (size_t)VV * DD, 0,
                 (size_t)(NPAD - VV) * DD * sizeof(bf16_t), stream);
  hipMemcpyAsync(PW, w_state, M1 * sizeof(float), hipMemcpyDeviceToDevice, stream);
  k_gatherF<<<NR, 256, 0, stream>>>(embed, ids, LOC);
  hipMemsetAsync(E0, 0, (size_t)PADR * DD * sizeof(float), stream);
  hipMemsetAsync(E1, 0, (size_t)PADR * DD * sizeof(float), stream);

  JobsF J{};
  J.j[0] = JobF{w_state, w_state, PW + M1, nullptr, KIND_SQ, 0};
  J.j[1] = JobF{LOC, w_state, LOC + M1, nullptr, KIND_ROUND, 1};
  k_multiF<<<dim3(16, 16, 2), 256, 0, stream>>>(J, embed, ids, HID);
  J.j[0] = JobF{PW + M1, w_state, PW + 2 * M1, nullptr, KIND_SQ, 0};
  J.j[1] = JobF{PW + M1, PW + M1, PW + 3 * M1, nullptr, KIND_SQ, 0};
  J.j[2] = JobF{LOC + M1, w_state, LOC + 2 * M1, nullptr, KIND_ROUND, 2};
  k_multiF<<<dim3(16, 16, 3), 256, 0, stream>>>(J, embed, ids, HID);
  J.j[0] = JobF{PW + 3 * M1, w_state, PW + 4 * M1, nullptr, KIND_SQ, 0};
  J.j[1] = JobF{PW + 3 * M1, PW + M1, PW + 5 * M1, nullptr, KIND_SQ, 0};
  J.j[2] = JobF{PW + 3 * M1, PW + 2 * M1, PW + 6 * M1, nullptr, KIND_SQ, 0};
  J.j[3] = JobF{PW + 3 * M1, PW + 3 * M1, PW + 7 * M1, nullptr, KIND_SQ, 0};
  J.j[4] = JobF{LOC + 2 * M1, w_state, LOC + 3 * M1, nullptr, KIND_ROUND, 3};
  k_multiF<<<dim3(16, 16, 5), 256, 0, stream>>>(J, embed, ids, HID);
  for (int d = 4; d <= 7; ++d) {
    const float* src = (d == 4) ? (PW + 7 * M1) : (Q + (size_t)(d - 5) * M1);
    J.j[0] = JobF{src, src, Q + (size_t)(d - 4) * M1, nullptr, KIND_SQ, 0};
    J.j[1] = JobF{LOC + (size_t)(d - 1) * M1, w_state, LOC + (size_t)d * M1,
                  nullptr, KIND_ROUND, d};
    k_multiF<<<dim3(16, 16, 2), 256, 0, stream>>>(J, embed, ids, HID);
  }
  hipMemcpyAsync(E0d, LOC + 7 * M1, M1 * sizeof(float),
                 hipMemcpyDeviceToDevice, stream);

  float* inp = E0d;
  float* outp = E1d;
  for (int k = 0; k < 8; ++k) {
    JobsF J2{};
    int nz = 0;
    if (k <= 2) {
      const float* src = Q + (size_t)(k + 3) * M1;
      J2.j[nz++] = JobF{src, src, Q + (size_t)(k + 4) * M1, nullptr, KIND_SQ, 0};
    }
    const float* Bq = (k == 0) ? (PW + 7 * M1) : (Q + (size_t)(k - 1) * M1);
    J2.j[nz++] = JobF{inp - (size_t)(4 << k) * DD, Bq, outp, inp, KIND_LEVEL, 0};
    k_multiF<<<dim3(16, 16, nz), 256, 0, stream>>>(J2, embed, ids, HID);
    float* t = inp; inp = outp; outp = t;
  }

  JobsF Jc{};
  for (int d = 0; d < 8; ++d)
    Jc.j[d] = JobF{inp - (size_t)4 * DD, PW + (size_t)d * M1, nullptr,
                   LOC + (size_t)d * M1, KIND_CARRY, d};
  k_multiF<<<dim3(16, 16, 8), 256, 0, stream>>>(Jc, embed, ids, HID);

  dim3 gl(NPAD / 256, (BB * TT) / 256);
  k_lmhead2<<<gl, 512, 0, stream>>>(HID, LWB, lm_b, out);
}

// Round 13
// 892.629 us; speedup vs baseline: 1.0964x; 1.0108x over previous
//
#include <hip/hip_runtime.h>
#include <hip/hip_bf16.h>
#include <stdint.h>

#define DD 1024   // hidden dim
#define BB 4      // batch
#define TT 2048   // seq len
#define VV 16000  // vocab
#define LCH 4     // chunk length (round 13: 8 -> 4)
#define NR 2048   // BB*(TT/LCH) rows, r = c*4 + b
#define PADR 1024 // zero pad rows before E buffers (max level shift 4<<8)
#define NPAD 16128
#define M1C ((size_t)DD * DD)

typedef __bf16 bf16_t;
typedef float f32x4_t __attribute__((ext_vector_type(4)));
typedef bf16_t bf16x8_t __attribute__((ext_vector_type(8)));
typedef bf16_t bf16x4_t __attribute__((ext_vector_type(4)));

#define KIND_SQ 0
#define KIND_ROUND 1
#define KIND_LEVEL 2
#define KIND_CARRY 3

__device__ __forceinline__ void gload16(const void* g, void* l) {
  __builtin_amdgcn_global_load_lds((const __attribute__((address_space(1))) void*)g,
                                   (__attribute__((address_space(3))) void*)l, 16, 0, 0);
}

// ---------------- fp32 -> bf16 convert (lm_w) ----------------
__global__ __launch_bounds__(256) void k_cvt(const float* __restrict__ src,
                                             bf16_t* __restrict__ dst, int n4) {
  int i = blockIdx.x * blockDim.x + threadIdx.x;
  int stride = gridDim.x * blockDim.x;
  for (; i < n4; i += stride) {
    float4 v = ((const float4*)src)[i];
    union { ushort4 u; bf16_t h[4]; } p;
    p.h[0] = (bf16_t)v.x; p.h[1] = (bf16_t)v.y;
    p.h[2] = (bf16_t)v.z; p.h[3] = (bf16_t)v.w;
    ((ushort4*)dst)[i] = p.u;
  }
}

// ---------------- chain: fp32-in/out split-bf16 MFMA GEMMs (round-5 verified) --
struct JobF {
  const float* A; const float* B; float* C; const float* Cin;
  int kind; int dlt;
};
struct JobsF { JobF j[8]; };

__global__ __launch_bounds__(256) void k_gatherF(const float* __restrict__ embed,
                                                 const int* __restrict__ ids,
                                                 float* __restrict__ slab0) {
  int r = blockIdx.x;
  int b = r & 3, c = r >> 2;
  int id = ids[b * TT + c * LCH];
  const float4* s = (const float4*)(embed + (size_t)id * DD);
  float4* d = (float4*)(slab0 + (size_t)r * DD);
  for (int i = threadIdx.x; i < DD / 4; i += blockDim.x) d[i] = s[i];
}

template <int NS>
__device__ __forceinline__ void swrite(char* base, int byteoff, float4 v) {
  float r0 = v.x, r1 = v.y, r2 = v.z, r3 = v.w;
#pragma unroll
  for (int p = 0; p < NS; ++p) {
    bf16x4_t h;
    h[0] = (bf16_t)r0; h[1] = (bf16_t)r1; h[2] = (bf16_t)r2; h[3] = (bf16_t)r3;
    *(bf16x4_t*)(base + p * 5120 + byteoff) = h;
    if (p + 1 < NS) {
      r0 -= (float)h[0]; r1 -= (float)h[1]; r2 -= (float)h[2]; r3 -= (float)h[3];
    }
  }
}

template <int NS, bool NN, int MODE>  // MODE: 0 plain,1 round,2 level,3 carry
__device__ __forceinline__ void mbodyF(bf16_t* __restrict__ SBb, const JobF& jb,
                                       const float* __restrict__ embed,
                                       const int* __restrict__ ids,
                                       bf16_t* __restrict__ hidden) {
  const float* A = jb.A;
  const float* Bm = jb.B;
  const int tid = threadIdx.x, lane = tid & 63, wave = tid >> 6;
  const int i0 = blockIdx.y * 64, j0 = blockIdx.x * 64;
  const int wm = (wave >> 1) * 32, wn = (wave & 1) * 32;
  char* Ap = (char*)SBb;
  char* Bp = Ap + NS * 5120;
  const int arow = tid >> 2;
  const int akb = (tid & 3) * 8;
  const int bj = tid & 63, bk4 = (tid >> 6) * 4;
  const int frow = lane & 15, fkb = (lane >> 4) * 16;
  f32x4_t acc[2][2] = {};

  const float* Aptr = A + (size_t)(i0 + arow) * DD + (tid & 3) * 4;
  const float* BptrNT = Bm + (size_t)(j0 + arow) * DD + (tid & 3) * 4;
  const float* BptrNN = Bm + (size_t)bk4 * DD + j0 + bj;

  float4 a0 = *(const float4*)(Aptr);
  float4 a1 = *(const float4*)(Aptr + 16);
  float4 b0, b1;
  float s0[4], s1[4];
  if (!NN) {
    b0 = *(const float4*)(BptrNT);
    b1 = *(const float4*)(BptrNT + 16);
  } else {
#pragma unroll
    for (int s = 0; s < 4; ++s) s0[s] = BptrNN[(size_t)s * DD];
#pragma unroll
    for (int s = 0; s < 4; ++s) s1[s] = BptrNN[(size_t)(16 + s) * DD];
  }

  for (int k0 = 0;;) {
    __syncthreads();
    swrite<NS>(Ap, arow * 80 + akb, a0);
    swrite<NS>(Ap, arow * 80 + akb + 32, a1);
    if (!NN) {
      swrite<NS>(Bp, arow * 80 + akb, b0);
      swrite<NS>(Bp, arow * 80 + akb + 32, b1);
    } else {
      float4 t0; t0.x = s0[0]; t0.y = s0[1]; t0.z = s0[2]; t0.w = s0[3];
      float4 t1; t1.x = s1[0]; t1.y = s1[1]; t1.z = s1[2]; t1.w = s1[3];
      swrite<NS>(Bp, bj * 80 + bk4 * 2, t0);
      swrite<NS>(Bp, bj * 80 + bk4 * 2 + 32, t1);
    }
    __syncthreads();
    int kn = k0 + 32;
    if (kn < DD) {
      a0 = *(const float4*)(Aptr + kn);
      a1 = *(const float4*)(Aptr + kn + 16);
      if (!NN) {
        b0 = *(const float4*)(BptrNT + kn);
        b1 = *(const float4*)(BptrNT + kn + 16);
      } else {
#pragma unroll
        for (int s = 0; s < 4; ++s) s0[s] = BptrNN[(size_t)(kn + s) * DD];
#pragma unroll
        for (int s = 0; s < 4; ++s) s1[s] = BptrNN[(size_t)(kn + 16 + s) * DD];
      }
    }
    bf16x8_t af[NS][2], bfx[NS][2];
#pragma unroll
    for (int p = 0; p < NS; ++p)
#pragma unroll
      for (int mf = 0; mf < 2; ++mf) {
        af[p][mf] = *(const bf16x8_t*)(Ap + p * 5120 + (wm + mf * 16 + frow) * 80 + fkb);
        bfx[p][mf] = *(const bf16x8_t*)(Bp + p * 5120 + (wn + mf * 16 + frow) * 80 + fkb);
      }
#pragma unroll
    for (int pa = 0; pa < NS; ++pa)
#pragma unroll
      for (int pb = 0; pb < NS; ++pb) {
        if (pa + pb < NS) {
#pragma unroll
          for (int mf = 0; mf < 2; ++mf)
#pragma unroll
            for (int nf = 0; nf < 2; ++nf)
              acc[mf][nf] = __builtin_amdgcn_mfma_f32_16x16x32_bf16(
                  af[pa][mf], bfx[pb][nf], acc[mf][nf], 0, 0, 0);
        }
      }
    k0 = kn;
    if (k0 >= DD) break;
  }

  const int ecol = lane & 15, er4 = (lane >> 4) * 4;
#pragma unroll
  for (int mf = 0; mf < 2; ++mf) {
#pragma unroll
    for (int nf = 0; nf < 2; ++nf) {
      const int rb = i0 + wm + mf * 16 + er4;
      const int cj = j0 + wn + nf * 16 + ecol;
#pragma unroll
      for (int rg = 0; rg < 4; ++rg) {
        const int ri = rb + rg;
        float v = acc[mf][nf][rg];
        if (MODE == 0) {
          jb.C[(size_t)ri * DD + cj] = v;
        } else if (MODE == 1) {
          int b = ri & 3, c = ri >> 2, t = c * LCH + jb.dlt;
          v += embed[(size_t)ids[b * TT + t] * DD + cj];
          jb.C[(size_t)ri * DD + cj] = v;
        } else if (MODE == 2) {
          v += jb.Cin[(size_t)ri * DD + cj];
          jb.C[(size_t)ri * DD + cj] = v;
        } else {
          int b = ri & 3, c = ri >> 2, t = c * LCH + jb.dlt;
          hidden[((size_t)b * TT + t) * DD + cj] =
              (bf16_t)(v + jb.Cin[(size_t)ri * DD + cj]);
        }
      }
    }
  }
}

__global__ __launch_bounds__(256, 2) void k_multiF(JobsF jobs,
                                                   const float* __restrict__ embed,
                                                   const int* __restrict__ ids,
                                                   bf16_t* __restrict__ hidden) {
  __shared__ __align__(16) bf16_t SBb[6 * 2560];
  const JobF& jb = jobs.j[blockIdx.z];
  // SQ units produce 1024x1024; grid y now spans NR/64 = 32 rows of tiles.
  if (jb.kind == KIND_SQ) {
    if (blockIdx.y >= 16) return;
    mbodyF<3, true, 0>(SBb, jb, embed, ids, hidden);
  } else if (jb.kind == KIND_ROUND)
    mbodyF<2, false, 1>(SBb, jb, embed, ids, hidden);
  else if (jb.kind == KIND_LEVEL)
    mbodyF<2, false, 2>(SBb, jb, embed, ids, hidden);
  else
    mbodyF<2, false, 3>(SBb, jb, embed, ids, hidden);
}

// ---------------- LM head: round-5 verified kernel (330 us) ------------------
#define NTK 32

__global__ __launch_bounds__(512, 2) void k_lmhead2(
    const bf16_t* __restrict__ Ah, const bf16_t* __restrict__ Bw,
    const float* __restrict__ bias, float* __restrict__ Cout) {
  __shared__ __align__(16) char LB[4 * 32768];
  const int tid = threadIdx.x, lane = tid & 63, wave = tid >> 6;
  const int wr = wave >> 2, wc = wave & 3;
  int orig = blockIdx.y * gridDim.x + blockIdx.x;
  int swz = (orig & 7) * 252 + (orig >> 3);
  int by = swz / 63, bx = swz % 63;
  const int m0 = by * 256, n0 = bx * 256;

  const int srow = tid >> 2;
  const int scb = (tid & 3) * 16;

  auto stage = [&](int t) {
    char* buf = LB + (size_t)(t & 3) * 32768;
#pragma unroll
    for (int p = 0; p < 2; ++p) {
      int row = p * 128 + srow;
      int sw = ((row >> 1) & 3) << 4;
      gload16((const char*)Ah + ((size_t)(m0 + row) * DD + t * 32) * 2 + (scb ^ sw),
              buf + p * 8192 + wave * 1024);
      gload16((const char*)Bw + ((size_t)(n0 + row) * DD + t * 32) * 2 + (scb ^ sw),
              buf + 16384 + p * 8192 + wave * 1024);
    }
  };

  const int frow = lane & 15;
  const int c4b = (lane >> 4) * 16;
  f32x4_t acc[8][4] = {};

  stage(0); stage(1); stage(2);
  asm volatile("s_waitcnt vmcnt(8)\ns_barrier" ::: "memory");

  for (int t = 0; t < NTK; ++t) {
    char* Abuf = LB + (size_t)(t & 3) * 32768;
    char* Bbuf = Abuf + 16384;
    if (t + 3 < NTK) stage(t + 3);
    bf16x8_t afr[4], bfr[4];
#pragma unroll
    for (int nf = 0; nf < 4; ++nf) {
      int r = wc * 64 + nf * 16 + frow;
      bfr[nf] = *(const bf16x8_t*)(Bbuf + r * 64 + (c4b ^ (((r >> 1) & 3) << 4)));
    }
#pragma unroll
    for (int mf = 0; mf < 4; ++mf) {
      int r = wr * 128 + mf * 16 + frow;
      afr[mf] = *(const bf16x8_t*)(Abuf + r * 64 + (c4b ^ (((r >> 1) & 3) << 4)));
    }
    __builtin_amdgcn_s_setprio(1);
#pragma unroll
    for (int mf = 0; mf < 4; ++mf)
#pragma unroll
      for (int nf = 0; nf < 4; ++nf)
        acc[mf][nf] = __builtin_amdgcn_mfma_f32_16x16x32_bf16(
            afr[mf], bfr[nf], acc[mf][nf], 0, 0, 0);
    __builtin_amdgcn_s_setprio(0);
#pragma unroll
    for (int mf = 0; mf < 4; ++mf) {
      int r = wr * 128 + 64 + mf * 16 + frow;
      afr[mf] = *(const bf16x8_t*)(Abuf + r * 64 + (c4b ^ (((r >> 1) & 3) << 4)));
    }
    __builtin_amdgcn_s_setprio(1);
#pragma unroll
    for (int mf = 0; mf < 4; ++mf)
#pragma unroll
      for (int nf = 0; nf < 4; ++nf)
        acc[4 + mf][nf] = __builtin_amdgcn_mfma_f32_16x16x32_bf16(
            afr[mf], bfr[nf], acc[4 + mf][nf], 0, 0, 0);
    __builtin_amdgcn_s_setprio(0);
    if (t < NTK - 3) {
      asm volatile("s_waitcnt vmcnt(8)\ns_barrier" ::: "memory");
    } else if (t == NTK - 3) {
      asm volatile("s_waitcnt vmcnt(4)\ns_barrier" ::: "memory");
    } else if (t == NTK - 2) {
      asm volatile("s_waitcnt vmcnt(0)\ns_barrier" ::: "memory");
    }
  }

  const int ecol = lane & 15, er4 = (lane >> 4) * 4;
#pragma unroll
  for (int mf = 0; mf < 8; ++mf) {
#pragma unroll
    for (int nf = 0; nf < 4; ++nf) {
      int gm = m0 + wr * 128 + mf * 16 + er4;
      int gn = n0 + wc * 64 + nf * 16 + ecol;
      if (gn < VV) {
        float bv = bias[gn];
#pragma unroll
        for (int rg = 0; rg < 4; ++rg)
          Cout[(size_t)(gm + rg) * VV + gn] = acc[mf][nf][rg] + bv;
      }
    }
  }
}

// ---------------- host orchestration (LCH=4 schedule) ------------------------
extern "C" void kernel_launch(void* const* d_in, const int* in_sizes, int n_in,
                              void* d_out, int out_size, void* d_ws, size_t ws_size,
                              hipStream_t stream) {
  (void)in_sizes; (void)n_in; (void)out_size; (void)ws_size;
  const int* ids = (const int*)d_in[0];
  const float* embed = (const float*)d_in[1];
  const float* w_state = (const float*)d_in[2];
  const float* lm_w = (const float*)d_in[3];
  const float* lm_b = (const float*)d_in[4];
  float* out = (float*)d_out;

  const size_t M1 = M1C;
  // POW slots: [0]=W^2 [1]=W^3 [2]=W^4 [3]=W^8 [4]=W^16 ... [10]=W^1024
  float* POW = (float*)d_ws;                // 11*M1 fp32
  float* LOC = POW + 11 * M1;               // 4 slabs * (NR*DD = 2*M1)
  float* E0 = LOC + 8 * M1;                 // (PADR+NR)*DD = 3*M1
  float* E1 = E0 + 3 * M1;                  // 3*M1
  bf16_t* HID = (bf16_t*)(E1 + 3 * M1);     // 8*M1 bf16
  bf16_t* LWB = HID + 8 * M1;               // NPAD*DD bf16
  float* E0d = E0 + (size_t)PADR * DD;
  float* E1d = E1 + (size_t)PADR * DD;
  // total: 25*M1*4 + 16.8MB + 33.0MB = 154.7 MB < 158.9 MB (round-5 proven)

  k_cvt<<<2048, 256, 0, stream>>>(lm_w, LWB, VV * DD / 4);
  hipMemsetAsync(LWB + (size_t)VV * DD, 0,
                 (size_t)(NPAD - VV) * DD * sizeof(bf16_t), stream);
  k_gatherF<<<NR, 256, 0, stream>>>(embed, ids, LOC);
  hipMemsetAsync(E0, 0, (size_t)PADR * DD * sizeof(float), stream);
  hipMemsetAsync(E1, 0, (size_t)PADR * DD * sizeof(float), stream);

  JobsF J{};
  // L1: W^2 = W*W | round d=1
  J.j[0] = JobF{w_state, w_state, POW, nullptr, KIND_SQ, 0};
  J.j[1] = JobF{LOC, w_state, LOC + 2 * M1, nullptr, KIND_ROUND, 1};
  k_multiF<<<dim3(16, 32, 2), 256, 0, stream>>>(J, embed, ids, HID);
  // L2: W^3 = W^2*W ; W^4 = W^2*W^2 | round d=2
  J.j[0] = JobF{POW, w_state, POW + M1, nullptr, KIND_SQ, 0};
  J.j[1] = JobF{POW, POW, POW + 2 * M1, nullptr, KIND_SQ, 0};
  J.j[2] = JobF{LOC + 2 * M1, w_state, LOC + 4 * M1, nullptr, KIND_ROUND, 2};
  k_multiF<<<dim3(16, 32, 3), 256, 0, stream>>>(J, embed, ids, HID);
  // L3: W^8 = (W^4)^2 | round d=3
  J.j[0] = JobF{POW + 2 * M1, POW + 2 * M1, POW + 3 * M1, nullptr, KIND_SQ, 0};
  J.j[1] = JobF{LOC + 4 * M1, w_state, LOC + 6 * M1, nullptr, KIND_ROUND, 3};
  k_multiF<<<dim3(16, 32, 2), 256, 0, stream>>>(J, embed, ids, HID);

  // E0 data = LOC slab 3 (chunk ends)
  hipMemcpyAsync(E0d, LOC + 6 * M1, 2 * M1 * sizeof(float),
                 hipMemcpyDeviceToDevice, stream);

  // levels k=0..8 over 512 chunks; Q_k = W^{4*2^k} = POW[k+2].
  // Fused squaring in S_k (k<=6): POW[k+4] = POW[k+3]^2  (W^16..W^1024).
  float* inp = E0d;
  float* outp = E1d;
  for (int k = 0; k < 9; ++k) {
    JobsF J2{};
    int nz = 0;
    J2.j[nz++] = JobF{inp - (size_t)(4 << k) * DD, POW + (size_t)(k + 2) * M1,
                      outp, inp, KIND_LEVEL, 0};
    if (k <= 6)
      J2.j[nz++] = JobF{POW + (size_t)(k + 3) * M1, POW + (size_t)(k + 3) * M1,
                        POW + (size_t)(k + 4) * M1, nullptr, KIND_SQ, 0};
    k_multiF<<<dim3(16, 32, nz), 256, 0, stream>>>(J2, embed, ids, HID);
    float* t = inp; inp = outp; outp = t;
  }
  // prefix ends in inp (E1d after 9 swaps)

  // carry-apply: hidden[b][c*4+d] = LOC[d][r] + E_{c-1} @ (W^{d+1})^T
  JobsF Jc{};
  Jc.j[0] = JobF{inp - (size_t)4 * DD, w_state, nullptr, LOC, KIND_CARRY, 0};
  for (int d = 1; d < LCH; ++d)
    Jc.j[d] = JobF{inp - (size_t)4 * DD, POW + (size_t)(d - 1) * M1, nullptr,
                   LOC + (size_t)d * 2 * M1, KIND_CARRY, d};
  k_multiF<<<dim3(16, 32, LCH), 256, 0, stream>>>(Jc, embed, ids, HID);

  // LM head
  dim3 gl(NPAD / 256, (BB * TT) / 256);
  k_lmhead2<<<gl, 512, 0, stream>>>(HID, LWB, lm_b, out);
}